// Round 2
// 473.298 us; speedup vs baseline: 1.0007x; 1.0007x over previous
//
#include <hip/hip_runtime.h>

// Problem constants: B=16, NF=64, EC=3, H=W=256, NF1=8, NF2=16
#define HW 65536           // H*W
#define NPIX (16 * HW)     // B*H*W = 1,048,576 pixels
#define THREADS 256

// Theory (R1 resubmit; R1 bench was an infra failure, no data):
// R0 kernel was memory-LATENCY bound (1.16 TB/s achieved vs 6.3
// achievable; implied VALUBusy ~15%). Changes vs R0:
//  - PX=1 (f2d drops 64->32 VGPR -> more waves/SIMD)
//  - o-loop chunked by 8 with double-buffered fm prefetch (8 loads in
//    flight per wave through each chunk's compute -> MLP ~8KB/SIMD)
//  - add-path (wa,ba,accum) in fp32: out error from `add` is linear,
//    <=~0.03 abs at absmax=27648. mul/den path stays fp64 (bit-identical
//    to the passing R0 kernel).

__device__ __forceinline__ double leakyd(double x) {
    // exactly where(x>=0, x, 0.2*x)
    return fmax(x, 0.2 * x);
}

__global__ __launch_bounds__(THREADS, 4) void attcnn_kernel(
    const float* __restrict__ fm,   // (16,64,256,256)
    const float* __restrict__ ex,   // (16,3,256,256)
    const float* __restrict__ w1,   // (8,3)
    const float* __restrict__ b1,   // (8,)
    const float* __restrict__ w2,   // (16,8)
    const float* __restrict__ b2,   // (16,)
    const float* __restrict__ wm,   // (64,16)
    const float* __restrict__ bm,   // (64,)
    const float* __restrict__ wa,   // (64,16)
    const float* __restrict__ ba,   // (64,)
    float* __restrict__ out)        // (16,64,256,256)
{
    __shared__ double s_w1[24];
    __shared__ double s_b1[8];
    __shared__ double s_w2[128];
    __shared__ double s_b2[16];
    __shared__ double s_wm[1024];
    __shared__ double s_bm[64];
    __shared__ float  s_wa[1024];   // add-path weights stay fp32
    __shared__ float  s_ba[64];

    const int tid = threadIdx.x;
    if (tid < 24)  s_w1[tid] = (double)w1[tid];
    if (tid < 8)   s_b1[tid] = (double)b1[tid];
    if (tid < 128) s_w2[tid] = (double)w2[tid];
    if (tid < 16)  s_b2[tid] = (double)b2[tid];
    if (tid < 64)  { s_bm[tid] = (double)bm[tid]; s_ba[tid] = ba[tid]; }
    #pragma unroll
    for (int i = 0; i < 4; ++i) {
        s_wm[tid + i * 256] = (double)wm[tid + i * 256];
        s_wa[tid + i * 256] = wa[tid + i * 256];
    }
    __syncthreads();

    // One pixel per thread
    const int idx = blockIdx.x * THREADS + tid;   // 0 .. 1,048,575
    const int b   = idx >> 16;                    // idx / HW
    const int hw  = idx & 65535;                  // idx % HW

    // --- Stage 1: extra_maps (3 ch) -> fea1 (8), fp64 ---
    const float* exp_ = ex + (long)b * 3 * HW + hw;
    const double e0 = (double)exp_[0];
    const double e1 = (double)exp_[HW];
    const double e2 = (double)exp_[2 * HW];

    double f1v[8];
    #pragma unroll
    for (int j = 0; j < 8; ++j) {
        f1v[j] = leakyd(fma(s_w1[j * 3 + 0], e0,
                        fma(s_w1[j * 3 + 1], e1,
                        fma(s_w1[j * 3 + 2], e2, s_b1[j]))));
    }

    // --- Stage 2: fea1 (8) -> fea2 (16), fp64; fp32 mirror for add-path ---
    double f2d[16];
    float  f2s[16];
    #pragma unroll
    for (int k = 0; k < 16; ++k) {
        double acc = s_b2[k];
        #pragma unroll
        for (int j = 0; j < 8; ++j)
            acc = fma(s_w2[k * 8 + j], f1v[j], acc);
        acc = leakyd(acc);
        f2d[k] = acc;
        f2s[k] = (float)acc;
    }

    // --- Stage 3: 64 output channels, chunked by 8 with double-buffered
    //     fm prefetch so 8 global loads stay in flight per wave ---
    const float* fmp = fm  + (long)b * 64 * HW + hw;
    float*       op  = out + (long)b * 64 * HW + hw;

    float fcur[8], fnxt[8];
    #pragma unroll
    for (int i = 0; i < 8; ++i) fcur[i] = fmp[(long)i * HW];

    #pragma unroll 1   // keep chunk loop rolled; explicit dbuf does the pipelining
    for (int c = 0; c < 8; ++c) {
        const int ob = c * 8;
        if (c < 7) {
            #pragma unroll
            for (int i = 0; i < 8; ++i)
                fnxt[i] = fmp[(long)(ob + 8 + i) * HW];
        }
        #pragma unroll
        for (int i = 0; i < 8; ++i) {
            const int o = ob + i;
            double m = s_bm[o];          // mul path: fp64 (precision-critical)
            float  a = s_ba[o];          // add path: fp32 (error is linear)
            #pragma unroll
            for (int k = 0; k < 16; ++k) {
                m = fma(s_wm[o * 16 + k], f2d[k], m);
                a = fmaf(s_wa[o * 16 + k], f2s[k], a);
            }
            const double den = fma((double)fcur[i], m, 1.0);
            float h = (float)den;        // exact relative conversion
            float r = __builtin_amdgcn_rcpf(h);
            r = r * fmaf(-h, r, 2.0f);   // Newton: ~1 ulp fp32
            op[(long)o * HW] = a * r;
        }
        if (c < 7) {
            #pragma unroll
            for (int i = 0; i < 8; ++i) fcur[i] = fnxt[i];
        }
    }
}

extern "C" void kernel_launch(void* const* d_in, const int* in_sizes, int n_in,
                              void* d_out, int out_size, void* d_ws, size_t ws_size,
                              hipStream_t stream) {
    const float* fm = (const float*)d_in[0];
    const float* ex = (const float*)d_in[1];
    const float* w1 = (const float*)d_in[2];
    const float* b1 = (const float*)d_in[3];
    const float* w2 = (const float*)d_in[4];
    const float* b2 = (const float*)d_in[5];
    const float* wm = (const float*)d_in[6];
    const float* bm = (const float*)d_in[7];
    const float* wa = (const float*)d_in[8];
    const float* ba = (const float*)d_in[9];
    float* out = (float*)d_out;

    const int blocks = NPIX / THREADS;   // 4096
    attcnn_kernel<<<blocks, THREADS, 0, stream>>>(fm, ex, w1, b1, w2, b2,
                                                  wm, bm, wa, ba, out);
}

// Round 3
// 463.389 us; speedup vs baseline: 1.0221x; 1.0214x over previous
//
#include <hip/hip_runtime.h>

// Problem constants: B=16, NF=64, EC=3, H=W=256, NF1=8, NF2=16
#define HW 65536           // H*W
#define NPIX (16 * HW)     // B*H*W = 1,048,576 pixels
#define THREADS 256

// Theory (R2): dur_us = ~324us fixed harness fills + ~149us kernel (attcnn
// never appears in rocprof top-5, whose cutoff is 162us). R0/R1 both
// plateau at ~149us because both stream ~1024 broadcast LDS weight reads
// per pixel in the stage-3 loop (~90us/SIMD of LDS-pipe time, on par with
// the 87us HBM floor). This version removes LDS entirely:
//  - pre-kernel converts weights to fp64 once into d_ws (global)
//  - main kernel reads weights via uniform indices -> compiler emits
//    s_load (scalar K$ pipe; no LDS, no vector VMEM for weights)
//  - 2-way split accumulators (fp64 reorder ~1e-15 rel, harmless)
//  - nontemporal fm loads / out stores (pure streaming data)
// mul/denominator path stays fp64; add path fp32 (linear error, passed R1).

// ws layout: doubles first, then floats (offsets in elements)
#define DW1 0       // 24  w1 fp64
#define DB1 24      // 8   b1
#define DW2 32      // 128 w2
#define DB2 160     // 16  b2
#define DWM 176     // 1024 wm
#define DBM 1200    // 64  bm
#define NDBL 1264
#define FWA 0       // 1024 wa fp32
#define FBA 1024    // 64   ba

__device__ __forceinline__ double leakyd(double x) {
    // exactly where(x>=0, x, 0.2*x)
    return fmax(x, 0.2 * x);
}

__global__ __launch_bounds__(256) void cvt_weights(
    const float* __restrict__ w1, const float* __restrict__ b1,
    const float* __restrict__ w2, const float* __restrict__ b2,
    const float* __restrict__ wm, const float* __restrict__ bm,
    const float* __restrict__ wa, const float* __restrict__ ba,
    double* __restrict__ wd, float* __restrict__ wf)
{
    const int t = threadIdx.x;
    if (t < 24)  wd[DW1 + t] = (double)w1[t];
    if (t < 8)   wd[DB1 + t] = (double)b1[t];
    if (t < 128) wd[DW2 + t] = (double)w2[t];
    if (t < 16)  wd[DB2 + t] = (double)b2[t];
    if (t < 64)  wd[DBM + t] = (double)bm[t];
    if (t < 64)  wf[FBA + t] = ba[t];
    #pragma unroll
    for (int i = 0; i < 4; ++i) {
        wd[DWM + t + i * 256] = (double)wm[t + i * 256];
        wf[FWA + t + i * 256] = wa[t + i * 256];
    }
}

__global__ __launch_bounds__(THREADS, 4) void attcnn_kernel(
    const float* __restrict__ fm,   // (16,64,256,256)
    const float* __restrict__ ex,   // (16,3,256,256)
    const double* __restrict__ wd,  // fp64 weights in ws
    const float* __restrict__ wf,   // fp32 add-path weights in ws
    float* __restrict__ out)        // (16,64,256,256)
{
    // One pixel per thread
    const int idx = blockIdx.x * THREADS + threadIdx.x;  // 0 .. 1,048,575
    const int b   = idx >> 16;                           // idx / HW
    const int hw  = idx & 65535;                         // idx % HW

    // --- Stage 1: extra_maps (3 ch) -> fea1 (8), fp64 ---
    const float* exp_ = ex + (long)b * 3 * HW + hw;
    const double e0 = (double)exp_[0];
    const double e1 = (double)exp_[HW];
    const double e2 = (double)exp_[2 * HW];

    double f1v[8];
    #pragma unroll
    for (int j = 0; j < 8; ++j) {
        f1v[j] = leakyd(fma(wd[DW1 + j * 3 + 0], e0,
                        fma(wd[DW1 + j * 3 + 1], e1,
                        fma(wd[DW1 + j * 3 + 2], e2, wd[DB1 + j]))));
    }

    // --- Stage 2: fea1 (8) -> fea2 (16), fp64; fp32 mirror for add-path ---
    double f2d[16];
    float  f2s[16];
    #pragma unroll
    for (int k = 0; k < 16; ++k) {
        double acc = wd[DB2 + k];
        #pragma unroll
        for (int j = 0; j < 8; ++j)
            acc = fma(wd[DW2 + k * 8 + j], f1v[j], acc);
        acc = leakyd(acc);
        f2d[k] = acc;
        f2s[k] = (float)acc;
    }

    // --- Stage 3: 64 output channels, chunked by 8, double-buffered
    //     nontemporal fm prefetch; weights via uniform s_load ---
    const float* fmp = fm  + (long)b * 64 * HW + hw;
    float*       op  = out + (long)b * 64 * HW + hw;

    float fcur[8], fnxt[8];
    #pragma unroll
    for (int i = 0; i < 8; ++i)
        fcur[i] = __builtin_nontemporal_load(fmp + (long)i * HW);

    #pragma unroll 1   // keep chunk loop rolled; explicit dbuf does the pipelining
    for (int c = 0; c < 8; ++c) {
        const int ob = c * 8;
        if (c < 7) {
            #pragma unroll
            for (int i = 0; i < 8; ++i)
                fnxt[i] = __builtin_nontemporal_load(fmp + (long)(ob + 8 + i) * HW);
        }
        #pragma unroll
        for (int i = 0; i < 8; ++i) {
            const int o = ob + i;
            const double* wmr = wd + DWM + o * 16;
            const float*  war = wf + FWA + o * 16;
            // 2-way split accumulators (latency); fp64 mul path, fp32 add path
            double m0 = wd[DBM + o], m1 = 0.0;
            float  a0 = wf[FBA + o], a1 = 0.0f;
            #pragma unroll
            for (int k = 0; k < 16; k += 2) {
                m0 = fma(wmr[k],     f2d[k],     m0);
                m1 = fma(wmr[k + 1], f2d[k + 1], m1);
                a0 = fmaf(war[k],     f2s[k],     a0);
                a1 = fmaf(war[k + 1], f2s[k + 1], a1);
            }
            const double m = m0 + m1;
            const float  a = a0 + a1;
            const double den = fma((double)fcur[i], m, 1.0);
            float h = (float)den;        // exact relative conversion
            float r = __builtin_amdgcn_rcpf(h);
            r = r * fmaf(-h, r, 2.0f);   // Newton: ~1 ulp fp32
            __builtin_nontemporal_store(a * r, op + (long)o * HW);
        }
        if (c < 7) {
            #pragma unroll
            for (int i = 0; i < 8; ++i) fcur[i] = fnxt[i];
        }
    }
}

extern "C" void kernel_launch(void* const* d_in, const int* in_sizes, int n_in,
                              void* d_out, int out_size, void* d_ws, size_t ws_size,
                              hipStream_t stream) {
    const float* fm = (const float*)d_in[0];
    const float* ex = (const float*)d_in[1];
    const float* w1 = (const float*)d_in[2];
    const float* b1 = (const float*)d_in[3];
    const float* w2 = (const float*)d_in[4];
    const float* b2 = (const float*)d_in[5];
    const float* wm = (const float*)d_in[6];
    const float* bm = (const float*)d_in[7];
    const float* wa = (const float*)d_in[8];
    const float* ba = (const float*)d_in[9];
    float* out = (float*)d_out;

    double* wd = (double*)d_ws;
    float*  wf = (float*)(wd + NDBL);

    // Pre-kernel: convert weights into ws (1 block, ~us). Same stream ->
    // ordered before main kernel; dispatch-boundary coherence applies.
    cvt_weights<<<1, 256, 0, stream>>>(w1, b1, w2, b2, wm, bm, wa, ba, wd, wf);

    const int blocks = NPIX / THREADS;   // 4096
    attcnn_kernel<<<blocks, THREADS, 0, stream>>>(fm, ex, wd, wf, out);
}

// Round 4
// 462.162 us; speedup vs baseline: 1.0248x; 1.0027x over previous
//
#include <hip/hip_runtime.h>

// Problem constants: B=16, NF=64, EC=3, H=W=256, NF1=8, NF2=16
#define HW 65536           // H*W
#define NPIX (16 * HW)     // B*H*W = 1,048,576 pixels
#define THREADS 256

// Theory (R4): kernel portion ~123us vs ~95us mixed-stream HBM floor.
// R3's s_load change was +16% on the kernel (confirmed). Remaining gap:
//  (1) stage-1/2 MLP prologue (~700cy) had zero fm loads in flight ->
//      issue 16 fm channel loads BEFORE stage 1;
//  (2) prefetch depth was 8; now rolling depth-16 via fully-unrolled
//      channel loop (load o+16 before computing o), static reg indices;
//  (3) add-path fp32 FMAs now packed (v_pk_fma_f32) via ext_vector +
//      __builtin_elementwise_fma -> halves fp32 issue slots.
// mul/denominator path unchanged (fp64, bit-identical to passing R3).

// ws layout: doubles first, then floats (offsets in elements)
#define DW1 0       // 24  w1 fp64
#define DB1 24      // 8   b1
#define DW2 32      // 128 w2
#define DB2 160     // 16  b2
#define DWM 176     // 1024 wm
#define DBM 1200    // 64  bm
#define NDBL 1264
#define FWA 0       // 1024 wa fp32
#define FBA 1024    // 64   ba

typedef float v2f __attribute__((ext_vector_type(2)));

__device__ __forceinline__ double leakyd(double x) {
    // exactly where(x>=0, x, 0.2*x)
    return fmax(x, 0.2 * x);
}

__global__ __launch_bounds__(256) void cvt_weights(
    const float* __restrict__ w1, const float* __restrict__ b1,
    const float* __restrict__ w2, const float* __restrict__ b2,
    const float* __restrict__ wm, const float* __restrict__ bm,
    const float* __restrict__ wa, const float* __restrict__ ba,
    double* __restrict__ wd, float* __restrict__ wf)
{
    const int t = threadIdx.x;
    if (t < 24)  wd[DW1 + t] = (double)w1[t];
    if (t < 8)   wd[DB1 + t] = (double)b1[t];
    if (t < 128) wd[DW2 + t] = (double)w2[t];
    if (t < 16)  wd[DB2 + t] = (double)b2[t];
    if (t < 64)  wd[DBM + t] = (double)bm[t];
    if (t < 64)  wf[FBA + t] = ba[t];
    #pragma unroll
    for (int i = 0; i < 4; ++i) {
        wd[DWM + t + i * 256] = (double)wm[t + i * 256];
        wf[FWA + t + i * 256] = wa[t + i * 256];
    }
}

__global__ __launch_bounds__(THREADS, 4) void attcnn_kernel(
    const float* __restrict__ fm,   // (16,64,256,256)
    const float* __restrict__ ex,   // (16,3,256,256)
    const double* __restrict__ wd,  // fp64 weights in ws
    const float* __restrict__ wf,   // fp32 add-path weights in ws
    float* __restrict__ out)        // (16,64,256,256)
{
    // One pixel per thread
    const int idx = blockIdx.x * THREADS + threadIdx.x;  // 0 .. 1,048,575
    const int b   = idx >> 16;                           // idx / HW
    const int hw  = idx & 65535;                         // idx % HW

    const float* exp_ = ex + (long)b * 3 * HW + hw;
    const float* fmp  = fm  + (long)b * 64 * HW + hw;
    float*       op   = out + (long)b * 64 * HW + hw;

    // --- Issue all prologue loads up front: 3 ex + first 16 fm channels.
    //     The fm loads fly during the entire stage-1/2 MLP. ---
    const float ex0 = exp_[0];
    const float ex1 = exp_[HW];
    const float ex2 = exp_[2 * HW];

    float fv[64];   // static-indexed -> registers; ~16 live at a time
    #pragma unroll
    for (int i = 0; i < 16; ++i)
        fv[i] = __builtin_nontemporal_load(fmp + (long)i * HW);

    // --- Stage 1: extra_maps (3 ch) -> fea1 (8), fp64 ---
    const double e0 = (double)ex0;
    const double e1 = (double)ex1;
    const double e2 = (double)ex2;

    double f1v[8];
    #pragma unroll
    for (int j = 0; j < 8; ++j) {
        f1v[j] = leakyd(fma(wd[DW1 + j * 3 + 0], e0,
                        fma(wd[DW1 + j * 3 + 1], e1,
                        fma(wd[DW1 + j * 3 + 2], e2, wd[DB1 + j]))));
    }

    // --- Stage 2: fea1 (8) -> fea2 (16), fp64; packed fp32 mirror ---
    double f2d[16];
    #pragma unroll
    for (int k = 0; k < 16; ++k) {
        double acc = wd[DB2 + k];
        #pragma unroll
        for (int j = 0; j < 8; ++j)
            acc = fma(wd[DW2 + k * 8 + j], f1v[j], acc);
        f2d[k] = leakyd(acc);
    }
    v2f f2p[8];
    #pragma unroll
    for (int k2 = 0; k2 < 8; ++k2) {
        f2p[k2].x = (float)f2d[2 * k2];
        f2p[k2].y = (float)f2d[2 * k2 + 1];
    }

    // --- Stage 3: fully-unrolled 64 channels, rolling depth-16 prefetch ---
    #pragma unroll
    for (int o = 0; o < 64; ++o) {
        if (o + 16 < 64)
            fv[o + 16] = __builtin_nontemporal_load(fmp + (long)(o + 16) * HW);

        const double* wmr = wd + DWM + o * 16;
        const v2f*    war = (const v2f*)(wf + FWA + o * 16);   // 64B-aligned

        // mul path: fp64, 2-way split accumulators (precision-critical)
        double m0 = wd[DBM + o], m1 = 0.0;
        #pragma unroll
        for (int k = 0; k < 16; k += 2) {
            m0 = fma(wmr[k],     f2d[k],     m0);
            m1 = fma(wmr[k + 1], f2d[k + 1], m1);
        }
        const double m = m0 + m1;

        // add path: packed fp32 (error is linear; ~1e-7 rel)
        v2f av = { wf[FBA + o], 0.0f };
        #pragma unroll
        for (int k2 = 0; k2 < 8; ++k2)
            av = __builtin_elementwise_fma(war[k2], f2p[k2], av);
        const float a = av.x + av.y;

        const double den = fma((double)fv[o], m, 1.0);
        float h = (float)den;        // exact relative conversion
        float r = __builtin_amdgcn_rcpf(h);
        r = r * fmaf(-h, r, 2.0f);   // Newton: ~1 ulp fp32
        __builtin_nontemporal_store(a * r, op + (long)o * HW);
    }
}

extern "C" void kernel_launch(void* const* d_in, const int* in_sizes, int n_in,
                              void* d_out, int out_size, void* d_ws, size_t ws_size,
                              hipStream_t stream) {
    const float* fm = (const float*)d_in[0];
    const float* ex = (const float*)d_in[1];
    const float* w1 = (const float*)d_in[2];
    const float* b1 = (const float*)d_in[3];
    const float* w2 = (const float*)d_in[4];
    const float* b2 = (const float*)d_in[5];
    const float* wm = (const float*)d_in[6];
    const float* bm = (const float*)d_in[7];
    const float* wa = (const float*)d_in[8];
    const float* ba = (const float*)d_in[9];
    float* out = (float*)d_out;

    double* wd = (double*)d_ws;
    float*  wf = (float*)(wd + NDBL);

    // Pre-kernel: convert weights into ws (1 block, ~2us). Same stream ->
    // ordered before main kernel; dispatch-boundary coherence applies.
    cvt_weights<<<1, 256, 0, stream>>>(w1, b1, w2, b2, wm, bm, wa, ba, wd, wf);

    const int blocks = NPIX / THREADS;   // 4096
    attcnn_kernel<<<blocks, THREADS, 0, stream>>>(fm, ex, wd, wf, out);
}